// Round 10
// baseline (472.753 us; speedup 1.0000x reference)
//
#include <hip/hip_runtime.h>
#include <math.h>

#define Hn 256
#define NHn 4
#define HDn 64
#define DWn 32
#define DAn 32
#define DVn 32
#define DGn 64
#define Bqn 2
#define Qln 8
#define Tln 512
#define EBn 16
#define PD 8    // register prefetch depth for the backward scan

__device__ __forceinline__ float sigm(float x) { return 1.0f / (1.0f + expf(-x)); }

__device__ __forceinline__ float wsum64(float v) {
#pragma unroll
    for (int m = 32; m >= 1; m >>= 1) v += __shfl_xor(v, m, 64);
    return v;
}

// ---- DPP wave64 sum reduction (canonical GCN tree, all VALU-speed) -------------
// ctrl/rmask must be ICEs -> template parameters. old=0 zero-fills masked lanes.
template <int CTRL, int RMASK>
__device__ __forceinline__ float dpp_add(float x) {
    int s = __builtin_amdgcn_update_dpp(0, __builtin_bit_cast(int, x),
                                        CTRL, RMASK, 0xf, true);
    return x + __builtin_bit_cast(float, s);
}
__device__ __forceinline__ float wred_dpp(float x) {
    x = dpp_add<0x111, 0xf>(x);  // row_shr:1
    x = dpp_add<0x112, 0xf>(x);  // row_shr:2
    x = dpp_add<0x114, 0xf>(x);  // row_shr:4
    x = dpp_add<0x118, 0xf>(x);  // row_shr:8  -> lane15 of each row = row sum
    x = dpp_add<0x142, 0xa>(x);  // row_bcast:15 -> rows 1,3 += prev row sum
    x = dpp_add<0x143, 0xc>(x);  // row_bcast:31 -> rows 2,3 += lanes0-31 sum
    return x;                    // lane 63 holds the full 64-lane sum
}
__device__ __forceinline__ float bcast63(float x) {
    return __builtin_bit_cast(float,
        __builtin_amdgcn_readlane(__builtin_bit_cast(int, x), 63));
}

// ---------------- Kernel A: per (b,t): k, kk (normalized), vraw, sv ----------------
__global__ void kA(const float* __restrict__ keyval,
                   const float* __restrict__ x_k, const float* __restrict__ x_v,
                   const float* __restrict__ Wk, const float* __restrict__ Wv,
                   const float* __restrict__ v0, const float* __restrict__ v1,
                   const float* __restrict__ v2, const float* __restrict__ k_k,
                   float* __restrict__ k_g, float* __restrict__ kk_g,
                   float* __restrict__ vraw_g, float* __restrict__ sv_g) {
    int bt = blockIdx.x;              // b*Tl + t
    int t = bt & (Tln - 1);
    int c = threadIdx.x;              // channel 0..255

    __shared__ __align__(16) float xk_s[Hn];
    __shared__ __align__(16) float xv_s[Hn];
    __shared__ float hv_s[DVn];

    float hs = keyval[bt * Hn + c];
    float pv = (t > 0) ? keyval[(bt - 1) * Hn + c] : 0.0f;
    float d = pv - hs;
    xk_s[c] = fmaf(d, x_k[c], hs);
    xv_s[c] = fmaf(d, x_v[c], hs);
    __syncthreads();

    // hv[d] = xv @ v1, threads 0..31
    if (c < DVn) {
        float acc = 0.f;
#pragma unroll 8
        for (int j = 0; j < Hn; ++j) acc = fmaf(xv_s[j], v1[j * DVn + c], acc);
        hv_s[c] = acc;
    }

    // k and vraw matvecs (row c of Wk/Wv)
    float kacc = 0.f, vacc = 0.f;
    const float4* xk4 = (const float4*)xk_s;
    const float4* xv4 = (const float4*)xv_s;
    const float4* wk4 = (const float4*)(Wk + c * Hn);
    const float4* wv4 = (const float4*)(Wv + c * Hn);
#pragma unroll 8
    for (int j = 0; j < Hn / 4; ++j) {
        float4 xa = xk4[j], wa = wk4[j];
        kacc += xa.x * wa.x + xa.y * wa.y + xa.z * wa.z + xa.w * wa.w;
        float4 xb = xv4[j], wb = wv4[j];
        vacc += xb.x * wb.x + xb.y * wb.y + xb.z * wb.z + xb.w * wb.w;
    }
    __syncthreads();

    // sv = sigmoid(v0 + hv @ v2)
    float svacc = v0[c];
#pragma unroll 8
    for (int dd = 0; dd < DVn; ++dd) svacc = fmaf(hv_s[dd], v2[dd * Hn + c], svacc);
    float sv = sigm(svacc);

    // kk = (k * k_k) normalized per head; head == wave (64 consecutive channels)
    float kkraw = kacc * k_k[c];
    float ss = wsum64(kkraw * kkraw);
    float denom = fmaxf(sqrtf(ss), 1e-12f);
    float kk = kkraw / denom;

    int o = bt * Hn + c;
    k_g[o] = kacc;
    kk_g[o] = kk;
    vraw_g[o] = vacc;
    sv_g[o] = sv;
}

// ---- Kernel B: per (eb,t): coef4 = {ew, km, ck, kk} packed, vt precomputed -------
__global__ void kB(const float* __restrict__ query, const float* __restrict__ keyval,
                   const float* __restrict__ x_w, const float* __restrict__ x_a,
                   const float* __restrict__ w0, const float* __restrict__ w1,
                   const float* __restrict__ w2, const float* __restrict__ a0,
                   const float* __restrict__ a1, const float* __restrict__ a2,
                   const float* __restrict__ k_a,
                   const float* __restrict__ k_g, const float* __restrict__ kk_g,
                   const float* __restrict__ vraw_g, const float* __restrict__ sv_g,
                   const float* __restrict__ v_first,
                   float4* __restrict__ coef4, float* __restrict__ vt_g) {
    const float NEGC = -0.60653065971263342f;  // -exp(-0.5)
    int id = blockIdx.x;               // eb*Tl + t
    int eb = id >> 9, t = id & (Tln - 1);
    int b = eb >> 3;                   // eb / Ql
    int c = threadIdx.x;

    __shared__ __align__(16) float xw_s[Hn];
    __shared__ __align__(16) float xa_s[Hn];
    __shared__ float hw_s[DWn];
    __shared__ float ha_s[DAn];

    int bt = (b << 9) + t;
    float hs = keyval[bt * Hn + c];
    float q = query[eb * Hn + c];
    float d = q - hs;
    xw_s[c] = fmaf(d, x_w[c], hs);
    xa_s[c] = fmaf(d, x_a[c], hs);
    __syncthreads();

    if (c < DWn) {
        float acc = 0.f;
#pragma unroll 8
        for (int j = 0; j < Hn; ++j) acc = fmaf(xw_s[j], w1[j * DWn + c], acc);
        hw_s[c] = tanhf(acc);
    } else if (c < DWn + DAn) {
        int dd = c - DWn;
        float acc = 0.f;
#pragma unroll 8
        for (int j = 0; j < Hn; ++j) acc = fmaf(xa_s[j], a1[j * DAn + dd], acc);
        ha_s[dd] = acc;
    }
    __syncthreads();

    float wacc = w0[c], aacc = a0[c];
#pragma unroll 8
    for (int dd = 0; dd < DWn; ++dd) {
        wacc = fmaf(hw_s[dd], w2[dd * Hn + c], wacc);
        aacc = fmaf(ha_s[dd], a2[dd * Hn + c], aacc);
    }
    float w = NEGC * sigm(wacc);
    float a = sigm(aacc);

    int obt = bt * Hn + c;
    size_t oet = (size_t)id * Hn + c;
    float kv = k_g[obt];
    float kkv = kk_g[obt];
    float ew = expf(w);
    float km = kv * fmaf(a - 1.0f, k_a[c], 1.0f);
    float ck = kkv * a;
    coef4[oet] = make_float4(ew, km, ck, kkv);

    float vr = vraw_g[obt];
    float sv = sv_g[obt];
    float vf = v_first[oet];
    vt_g[oet] = fmaf(vf - vr, sv, vr);
}

// ---- Kernel R: per eb (t=T-1 only): r, g(gate), s_h bonus scalars ---------------
__global__ void kR(const float* __restrict__ query, const float* __restrict__ keyval,
                   const float* __restrict__ x_r, const float* __restrict__ x_g,
                   const float* __restrict__ Wr, const float* __restrict__ g1,
                   const float* __restrict__ g2, const float* __restrict__ r_k,
                   const float4* __restrict__ coef4,
                   float* __restrict__ r_g, float* __restrict__ g_g,
                   float* __restrict__ sh_g) {
    int eb = blockIdx.x;
    int b = eb >> 3;
    int c = threadIdx.x;

    __shared__ __align__(16) float xr_s[Hn];
    __shared__ __align__(16) float xg_s[Hn];
    __shared__ float hg_s[DGn];

    int btl = (b * Tln + (Tln - 1)) * Hn;
    float hs = keyval[btl + c];
    float q = query[eb * Hn + c];
    float d = q - hs;
    xr_s[c] = fmaf(d, x_r[c], hs);
    xg_s[c] = fmaf(d, x_g[c], hs);
    __syncthreads();

    float racc = 0.f;
    {
        const float4* xr4 = (const float4*)xr_s;
        const float4* wr4 = (const float4*)(Wr + c * Hn);
#pragma unroll 8
        for (int j = 0; j < Hn / 4; ++j) {
            float4 xa = xr4[j], wa = wr4[j];
            racc += xa.x * wa.x + xa.y * wa.y + xa.z * wa.z + xa.w * wa.w;
        }
    }

    if (c < DGn) {
        float gacc = 0.f;
#pragma unroll 8
        for (int j = 0; j < Hn; ++j) gacc = fmaf(xg_s[j], g1[j * DGn + c], gacc);
        hg_s[c] = sigm(gacc);
    }
    __syncthreads();

    float gv = 0.f;
#pragma unroll 8
    for (int dd = 0; dd < DGn; ++dd) gv = fmaf(hg_s[dd], g2[dd * Hn + c], gv);

    // s_h = sum over head channels of r * km(T-1) * r_k
    float kmv = coef4[((size_t)(eb * Tln + (Tln - 1))) * Hn + c].y;
    float part = wsum64(racc * kmv * r_k[c]);

    r_g[eb * Hn + c] = racc;
    g_g[eb * Hn + c] = gv;
    if ((c & 63) == 0) sh_g[eb * NHn + (c >> 6)] = part;
}

// ---- Kernel C: BACKWARD vector scan. 1 wave per (eb,h); lane = channel. ---------
// o = sum_t (u_t . km_t) vt_t,  u_{T-1} = r,  u_{t-1} = ew_t*u_t - (u_t . ck_t) kk_t
// Per step: 1 coalesced float4 + 1 float per lane (register-prefetched PD deep,
// statically indexed), two interleaved DPP tree reductions, 3 FMAs.
// No LDS, no barriers, no cross-lane DS ops.
__global__ __launch_bounds__(64) void kScan(
    const float4* __restrict__ coef, const float* __restrict__ vt_g,
    const float* __restrict__ r_g, float* __restrict__ o_raw) {
    int blk = blockIdx.x;            // eb*NH + h
    int eb = blk >> 2, h = blk & 3;
    int lane = threadIdx.x;

    const size_t base = ((size_t)eb * Tln + (Tln - 1)) * Hn + h * HDn + lane;

    float4 cb[PD];
    float  vb[PD];
#pragma unroll
    for (int j = 0; j < PD; ++j) {
        cb[j] = coef[base - (size_t)j * Hn];
        vb[j] = vt_g[base - (size_t)j * Hn];
    }

    float u = r_g[eb * Hn + h * HDn + lane];
    float o = 0.f;

#pragma unroll 1
    for (int tb = 0; tb < Tln; tb += PD) {
#pragma unroll
        for (int j = 0; j < PD; ++j) {
            float4 cf = cb[j];           // {ew, km, ck, kk} at t = T-1-(tb+j)
            float vt = vb[j];
            int tn = tb + j + PD;        // refill slot j for PD steps ahead
            if (tn < Tln) {
                cb[j] = coef[base - (size_t)tn * Hn];
                vb[j] = vt_g[base - (size_t)tn * Hn];
            }
            float p1 = u * cf.y;         // u .* km
            float p2 = u * cf.z;         // u .* ck
            float r1 = wred_dpp(p1);     // two independent trees -> interleaved
            float r2 = wred_dpp(p2);
            float s1 = bcast63(r1);      // u . km   (SGPR broadcast)
            float d  = bcast63(r2);      // u . ck
            o = fmaf(s1, vt, o);
            u = fmaf(u, cf.x, -(d * cf.w));   // u = ew*u - d*kk
        }
    }

    o_raw[eb * Hn + h * HDn + lane] = o;
}

// ---- Kernel D: groupnorm + bonus + gate, then @ Wo.T ---------------------------
__global__ void kD(const float* __restrict__ o_raw, const float* __restrict__ gn_w,
                   const float* __restrict__ gn_b, const float* __restrict__ sh_g,
                   const float* __restrict__ vt_g, const float* __restrict__ g_g,
                   const float* __restrict__ Wo, float* __restrict__ out) {
    const float EPSC = 64e-5f;  // HD * 1e-5
    int eb = blockIdx.x;
    int c = threadIdx.x;
    __shared__ __align__(16) float o_s[Hn];

    float o = o_raw[eb * Hn + c];
    float mu = wsum64(o) * (1.0f / HDn);
    float dev = o - mu;
    float var = wsum64(dev * dev) * (1.0f / HDn);
    float og = dev * rsqrtf(var + EPSC) * gn_w[c] + gn_b[c];

    float sh = sh_g[eb * NHn + (c >> 6)];
    float vtl = vt_g[((size_t)(eb * Tln + (Tln - 1))) * Hn + c];
    float o2 = fmaf(sh, vtl, og);
    o_s[c] = o2 * g_g[eb * Hn + c];
    __syncthreads();

    float acc = 0.f;
    const float4* o4 = (const float4*)o_s;
    const float4* w4 = (const float4*)(Wo + c * Hn);
#pragma unroll 8
    for (int j = 0; j < Hn / 4; ++j) {
        float4 xa = o4[j], wa = w4[j];
        acc += xa.x * wa.x + xa.y * wa.y + xa.z * wa.z + xa.w * wa.w;
    }
    out[eb * Hn + c] = acc;
}

extern "C" void kernel_launch(void* const* d_in, const int* in_sizes, int n_in,
                              void* d_out, int out_size, void* d_ws, size_t ws_size,
                              hipStream_t stream) {
    const float* query  = (const float*)d_in[0];
    const float* keyval = (const float*)d_in[1];
    const float* v_first= (const float*)d_in[2];
    const float* x_r = (const float*)d_in[3];
    const float* x_w = (const float*)d_in[4];
    const float* x_k = (const float*)d_in[5];
    const float* x_v = (const float*)d_in[6];
    const float* x_a = (const float*)d_in[7];
    const float* x_g = (const float*)d_in[8];
    const float* w0  = (const float*)d_in[9];
    const float* w1  = (const float*)d_in[10];
    const float* w2  = (const float*)d_in[11];
    const float* a0  = (const float*)d_in[12];
    const float* a1  = (const float*)d_in[13];
    const float* a2  = (const float*)d_in[14];
    const float* v0  = (const float*)d_in[15];
    const float* v1  = (const float*)d_in[16];
    const float* v2  = (const float*)d_in[17];
    const float* g1  = (const float*)d_in[18];
    const float* g2  = (const float*)d_in[19];
    const float* k_k = (const float*)d_in[20];
    const float* k_a = (const float*)d_in[21];
    const float* r_k = (const float*)d_in[22];
    const float* Wr  = (const float*)d_in[23];
    const float* Wk  = (const float*)d_in[24];
    const float* Wv  = (const float*)d_in[25];
    const float* Wo  = (const float*)d_in[26];
    const float* gn_w= (const float*)d_in[27];
    const float* gn_b= (const float*)d_in[28];

    float* ws = (float*)d_ws;
    const size_t BTH = (size_t)Bqn * Tln * Hn;     // 262144
    const size_t ETH = (size_t)EBn * Tln * Hn;     // 2097152

    float4* coef4 = (float4*)ws;                   // 4*ETH floats (16B-aligned base)
    float* vt_g   = ws + 4 * ETH;                  // ETH
    float* k_g    = ws + 5 * ETH;                  // BTH
    float* kk_g   = ws + 5 * ETH + BTH;
    float* vraw_g = ws + 5 * ETH + 2 * BTH;
    float* sv_g   = ws + 5 * ETH + 3 * BTH;
    float* r_g    = ws + 5 * ETH + 4 * BTH;        // EB*H
    float* g_g    = r_g + EBn * Hn;
    float* sh_g   = g_g + EBn * Hn;                // EB*NH
    float* o_raw  = sh_g + EBn * NHn;              // EB*H

    kA<<<Bqn * Tln, Hn, 0, stream>>>(keyval, x_k, x_v, Wk, Wv, v0, v1, v2, k_k,
                                     k_g, kk_g, vraw_g, sv_g);
    kB<<<EBn * Tln, Hn, 0, stream>>>(query, keyval, x_w, x_a, w0, w1, w2, a0, a1, a2,
                                     k_a, k_g, kk_g, vraw_g, sv_g, v_first,
                                     coef4, vt_g);
    kR<<<EBn, Hn, 0, stream>>>(query, keyval, x_r, x_g, Wr, g1, g2, r_k, coef4,
                               r_g, g_g, sh_g);
    kScan<<<EBn * NHn, HDn, 0, stream>>>(coef4, vt_g, r_g, o_raw);
    kD<<<EBn, Hn, 0, stream>>>(o_raw, gn_w, gn_b, sh_g, vt_g, g_g, Wo, (float*)d_out);
}

// Round 12
// 380.570 us; speedup vs baseline: 1.2422x; 1.2422x over previous
//
#include <hip/hip_runtime.h>
#include <math.h>

#define Hn 256
#define NHn 4
#define HDn 64
#define DWn 32
#define DAn 32
#define DVn 32
#define DGn 64
#define Bqn 2
#define Qln 8
#define Tln 512
#define EBn 16
#define PD 8    // register prefetch depth for the backward scan

__device__ __forceinline__ float sigm(float x) { return 1.0f / (1.0f + expf(-x)); }

__device__ __forceinline__ float wsum64(float v) {
#pragma unroll
    for (int m = 32; m >= 1; m >>= 1) v += __shfl_xor(v, m, 64);
    return v;
}

// ---- DPP wave64 sum reduction (canonical GCN tree, all VALU-speed) -------------
// ctrl/rmask must be ICEs -> template parameters. old=0 zero-fills masked lanes.
template <int CTRL, int RMASK>
__device__ __forceinline__ float dpp_add(float x) {
    int s = __builtin_amdgcn_update_dpp(0, __builtin_bit_cast(int, x),
                                        CTRL, RMASK, 0xf, true);
    return x + __builtin_bit_cast(float, s);
}
__device__ __forceinline__ float wred_dpp(float x) {
    x = dpp_add<0x111, 0xf>(x);  // row_shr:1
    x = dpp_add<0x112, 0xf>(x);  // row_shr:2
    x = dpp_add<0x114, 0xf>(x);  // row_shr:4
    x = dpp_add<0x118, 0xf>(x);  // row_shr:8  -> lane15 of each row = row sum
    x = dpp_add<0x142, 0xa>(x);  // row_bcast:15 -> rows 1,3 += prev row sum
    x = dpp_add<0x143, 0xc>(x);  // row_bcast:31 -> rows 2,3 += lanes0-31 sum
    return x;                    // lane 63 holds the full 64-lane sum
}
__device__ __forceinline__ float bcast63(float x) {
    return __builtin_bit_cast(float,
        __builtin_amdgcn_readlane(__builtin_bit_cast(int, x), 63));
}

// ---------------- Kernel A: per (b,t): k, kk (normalized), vraw, sv ----------------
__global__ void kA(const float* __restrict__ keyval,
                   const float* __restrict__ x_k, const float* __restrict__ x_v,
                   const float* __restrict__ Wk, const float* __restrict__ Wv,
                   const float* __restrict__ v0, const float* __restrict__ v1,
                   const float* __restrict__ v2, const float* __restrict__ k_k,
                   float* __restrict__ k_g, float* __restrict__ kk_g,
                   float* __restrict__ vraw_g, float* __restrict__ sv_g) {
    int bt = blockIdx.x;              // b*Tl + t
    int t = bt & (Tln - 1);
    int c = threadIdx.x;              // channel 0..255

    __shared__ __align__(16) float xk_s[Hn];
    __shared__ __align__(16) float xv_s[Hn];
    __shared__ float hv_s[DVn];

    float hs = keyval[bt * Hn + c];
    float pv = (t > 0) ? keyval[(bt - 1) * Hn + c] : 0.0f;
    float d = pv - hs;
    xk_s[c] = fmaf(d, x_k[c], hs);
    xv_s[c] = fmaf(d, x_v[c], hs);
    __syncthreads();

    // hv[d] = xv @ v1, threads 0..31
    if (c < DVn) {
        float acc = 0.f;
#pragma unroll 8
        for (int j = 0; j < Hn; ++j) acc = fmaf(xv_s[j], v1[j * DVn + c], acc);
        hv_s[c] = acc;
    }

    // k and vraw matvecs (row c of Wk/Wv)
    float kacc = 0.f, vacc = 0.f;
    const float4* xk4 = (const float4*)xk_s;
    const float4* xv4 = (const float4*)xv_s;
    const float4* wk4 = (const float4*)(Wk + c * Hn);
    const float4* wv4 = (const float4*)(Wv + c * Hn);
#pragma unroll 8
    for (int j = 0; j < Hn / 4; ++j) {
        float4 xa = xk4[j], wa = wk4[j];
        kacc += xa.x * wa.x + xa.y * wa.y + xa.z * wa.z + xa.w * wa.w;
        float4 xb = xv4[j], wb = wv4[j];
        vacc += xb.x * wb.x + xb.y * wb.y + xb.z * wb.z + xb.w * wb.w;
    }
    __syncthreads();

    // sv = sigmoid(v0 + hv @ v2)
    float svacc = v0[c];
#pragma unroll 8
    for (int dd = 0; dd < DVn; ++dd) svacc = fmaf(hv_s[dd], v2[dd * Hn + c], svacc);
    float sv = sigm(svacc);

    // kk = (k * k_k) normalized per head; head == wave (64 consecutive channels)
    float kkraw = kacc * k_k[c];
    float ss = wsum64(kkraw * kkraw);
    float denom = fmaxf(sqrtf(ss), 1e-12f);
    float kk = kkraw / denom;

    int o = bt * Hn + c;
    k_g[o] = kacc;
    kk_g[o] = kk;
    vraw_g[o] = vacc;
    sv_g[o] = sv;
}

// ---- Kernel B: per (eb,t): coef4 = {ew, km, ck, kk} packed, vt precomputed -------
__global__ void kB(const float* __restrict__ query, const float* __restrict__ keyval,
                   const float* __restrict__ x_w, const float* __restrict__ x_a,
                   const float* __restrict__ w0, const float* __restrict__ w1,
                   const float* __restrict__ w2, const float* __restrict__ a0,
                   const float* __restrict__ a1, const float* __restrict__ a2,
                   const float* __restrict__ k_a,
                   const float* __restrict__ k_g, const float* __restrict__ kk_g,
                   const float* __restrict__ vraw_g, const float* __restrict__ sv_g,
                   const float* __restrict__ v_first,
                   float4* __restrict__ coef4, float* __restrict__ vt_g) {
    const float NEGC = -0.60653065971263342f;  // -exp(-0.5)
    int id = blockIdx.x;               // eb*Tl + t
    int eb = id >> 9, t = id & (Tln - 1);
    int b = eb >> 3;                   // eb / Ql
    int c = threadIdx.x;

    __shared__ __align__(16) float xw_s[Hn];
    __shared__ __align__(16) float xa_s[Hn];
    __shared__ float hw_s[DWn];
    __shared__ float ha_s[DAn];

    int bt = (b << 9) + t;
    float hs = keyval[bt * Hn + c];
    float q = query[eb * Hn + c];
    float d = q - hs;
    xw_s[c] = fmaf(d, x_w[c], hs);
    xa_s[c] = fmaf(d, x_a[c], hs);
    __syncthreads();

    if (c < DWn) {
        float acc = 0.f;
#pragma unroll 8
        for (int j = 0; j < Hn; ++j) acc = fmaf(xw_s[j], w1[j * DWn + c], acc);
        hw_s[c] = tanhf(acc);
    } else if (c < DWn + DAn) {
        int dd = c - DWn;
        float acc = 0.f;
#pragma unroll 8
        for (int j = 0; j < Hn; ++j) acc = fmaf(xa_s[j], a1[j * DAn + dd], acc);
        ha_s[dd] = acc;
    }
    __syncthreads();

    float wacc = w0[c], aacc = a0[c];
#pragma unroll 8
    for (int dd = 0; dd < DWn; ++dd) {
        wacc = fmaf(hw_s[dd], w2[dd * Hn + c], wacc);
        aacc = fmaf(ha_s[dd], a2[dd * Hn + c], aacc);
    }
    float w = NEGC * sigm(wacc);
    float a = sigm(aacc);

    int obt = bt * Hn + c;
    size_t oet = (size_t)id * Hn + c;
    float kv = k_g[obt];
    float kkv = kk_g[obt];
    float ew = expf(w);
    float km = kv * fmaf(a - 1.0f, k_a[c], 1.0f);
    float ck = kkv * a;
    coef4[oet] = make_float4(ew, km, ck, kkv);

    float vr = vraw_g[obt];
    float sv = sv_g[obt];
    float vf = v_first[oet];
    vt_g[oet] = fmaf(vf - vr, sv, vr);
}

// ---- Kernel R: per eb (t=T-1 only): r, g(gate), s_h bonus scalars ---------------
__global__ void kR(const float* __restrict__ query, const float* __restrict__ keyval,
                   const float* __restrict__ x_r, const float* __restrict__ x_g,
                   const float* __restrict__ Wr, const float* __restrict__ g1,
                   const float* __restrict__ g2, const float* __restrict__ r_k,
                   const float4* __restrict__ coef4,
                   float* __restrict__ r_g, float* __restrict__ g_g,
                   float* __restrict__ sh_g) {
    int eb = blockIdx.x;
    int b = eb >> 3;
    int c = threadIdx.x;

    __shared__ __align__(16) float xr_s[Hn];
    __shared__ __align__(16) float xg_s[Hn];
    __shared__ float hg_s[DGn];

    int btl = (b * Tln + (Tln - 1)) * Hn;
    float hs = keyval[btl + c];
    float q = query[eb * Hn + c];
    float d = q - hs;
    xr_s[c] = fmaf(d, x_r[c], hs);
    xg_s[c] = fmaf(d, x_g[c], hs);
    __syncthreads();

    float racc = 0.f;
    {
        const float4* xr4 = (const float4*)xr_s;
        const float4* wr4 = (const float4*)(Wr + c * Hn);
#pragma unroll 8
        for (int j = 0; j < Hn / 4; ++j) {
            float4 xa = xr4[j], wa = wr4[j];
            racc += xa.x * wa.x + xa.y * wa.y + xa.z * wa.z + xa.w * wa.w;
        }
    }

    if (c < DGn) {
        float gacc = 0.f;
#pragma unroll 8
        for (int j = 0; j < Hn; ++j) gacc = fmaf(xg_s[j], g1[j * DGn + c], gacc);
        hg_s[c] = sigm(gacc);
    }
    __syncthreads();

    float gv = 0.f;
#pragma unroll 8
    for (int dd = 0; dd < DGn; ++dd) gv = fmaf(hg_s[dd], g2[dd * Hn + c], gv);

    // s_h = sum over head channels of r * km(T-1) * r_k
    float kmv = coef4[((size_t)(eb * Tln + (Tln - 1))) * Hn + c].y;
    float part = wsum64(racc * kmv * r_k[c]);

    r_g[eb * Hn + c] = racc;
    g_g[eb * Hn + c] = gv;
    if ((c & 63) == 0) sh_g[eb * NHn + (c >> 6)] = part;
}

// ---- Kernel C: BACKWARD vector scan. 1 wave per (eb,h); lane = channel. ---------
// o = sum_t (u_t . km_t) vt_t,  u_{T-1} = r,  u_{t-1} = ew_t*u_t - (u_t . ck_t) kk_t
// Refills are UNCONDITIONAL (coef/vt have PD*Hn padding below t=0) so the load
// stream is statically shaped -> compiler emits counted vmcnt, prefetch depth PD
// stays effective. uw = u*ew hoisted off the post-reduction critical path.
__global__ __launch_bounds__(64) void kScan(
    const float4* __restrict__ coef, const float* __restrict__ vt_g,
    const float* __restrict__ r_g, float* __restrict__ o_raw) {
    int blk = blockIdx.x;            // eb*NH + h
    int eb = blk >> 2, h = blk & 3;
    int lane = threadIdx.x;

    const size_t base = ((size_t)eb * Tln + (Tln - 1)) * Hn + h * HDn + lane;

    float4 cb[PD];
    float  vb[PD];
#pragma unroll
    for (int j = 0; j < PD; ++j) {
        cb[j] = coef[base - (size_t)j * Hn];
        vb[j] = vt_g[base - (size_t)j * Hn];
    }

    float u = r_g[eb * Hn + h * HDn + lane];
    float o = 0.f;

#pragma unroll 1
    for (int tb = 0; tb < Tln; tb += PD) {
#pragma unroll
        for (int j = 0; j < PD; ++j) {
            float4 cf = cb[j];           // {ew, km, ck, kk} at t = T-1-(tb+j)
            float vt = vb[j];
            int tn = tb + j + PD;        // refill slot j, PD steps ahead;
            cb[j] = coef[base - (size_t)tn * Hn];   // t<0 lands in pad (unused)
            vb[j] = vt_g[base - (size_t)tn * Hn];
            float p2 = u * cf.z;         // u .* ck   (critical chain)
            float uw = u * cf.x;         // ew*u, independent of d -> hoisted
            float p1 = u * cf.y;         // u .* km   (feeds o only)
            float r2 = wred_dpp(p2);
            float r1 = wred_dpp(p1);
            float d  = bcast63(r2);      // u . ck   (SGPR broadcast)
            float s1 = bcast63(r1);      // u . km
            o = fmaf(s1, vt, o);
            u = fmaf(-d, cf.w, uw);      // u = ew*u - d*kk  (1 dependent fma)
        }
    }

    o_raw[eb * Hn + h * HDn + lane] = o;
}

// ---- Kernel D: groupnorm + bonus + gate, then @ Wo.T ---------------------------
__global__ void kD(const float* __restrict__ o_raw, const float* __restrict__ gn_w,
                   const float* __restrict__ gn_b, const float* __restrict__ sh_g,
                   const float* __restrict__ vt_g, const float* __restrict__ g_g,
                   const float* __restrict__ Wo, float* __restrict__ out) {
    const float EPSC = 64e-5f;  // HD * 1e-5
    int eb = blockIdx.x;
    int c = threadIdx.x;
    __shared__ __align__(16) float o_s[Hn];

    float o = o_raw[eb * Hn + c];
    float mu = wsum64(o) * (1.0f / HDn);
    float dev = o - mu;
    float var = wsum64(dev * dev) * (1.0f / HDn);
    float og = dev * rsqrtf(var + EPSC) * gn_w[c] + gn_b[c];

    float sh = sh_g[eb * NHn + (c >> 6)];
    float vtl = vt_g[((size_t)(eb * Tln + (Tln - 1))) * Hn + c];
    float o2 = fmaf(sh, vtl, og);
    o_s[c] = o2 * g_g[eb * Hn + c];
    __syncthreads();

    float acc = 0.f;
    const float4* o4 = (const float4*)o_s;
    const float4* w4 = (const float4*)(Wo + c * Hn);
#pragma unroll 8
    for (int j = 0; j < Hn / 4; ++j) {
        float4 xa = o4[j], wa = w4[j];
        acc += xa.x * wa.x + xa.y * wa.y + xa.z * wa.z + xa.w * wa.w;
    }
    out[eb * Hn + c] = acc;
}

extern "C" void kernel_launch(void* const* d_in, const int* in_sizes, int n_in,
                              void* d_out, int out_size, void* d_ws, size_t ws_size,
                              hipStream_t stream) {
    const float* query  = (const float*)d_in[0];
    const float* keyval = (const float*)d_in[1];
    const float* v_first= (const float*)d_in[2];
    const float* x_r = (const float*)d_in[3];
    const float* x_w = (const float*)d_in[4];
    const float* x_k = (const float*)d_in[5];
    const float* x_v = (const float*)d_in[6];
    const float* x_a = (const float*)d_in[7];
    const float* x_g = (const float*)d_in[8];
    const float* w0  = (const float*)d_in[9];
    const float* w1  = (const float*)d_in[10];
    const float* w2  = (const float*)d_in[11];
    const float* a0  = (const float*)d_in[12];
    const float* a1  = (const float*)d_in[13];
    const float* a2  = (const float*)d_in[14];
    const float* v0  = (const float*)d_in[15];
    const float* v1  = (const float*)d_in[16];
    const float* v2  = (const float*)d_in[17];
    const float* g1  = (const float*)d_in[18];
    const float* g2  = (const float*)d_in[19];
    const float* k_k = (const float*)d_in[20];
    const float* k_a = (const float*)d_in[21];
    const float* r_k = (const float*)d_in[22];
    const float* Wr  = (const float*)d_in[23];
    const float* Wk  = (const float*)d_in[24];
    const float* Wv  = (const float*)d_in[25];
    const float* Wo  = (const float*)d_in[26];
    const float* gn_w= (const float*)d_in[27];
    const float* gn_b= (const float*)d_in[28];

    float* ws = (float*)d_ws;
    const size_t BTH = (size_t)Bqn * Tln * Hn;     // 262144
    const size_t ETH = (size_t)EBn * Tln * Hn;     // 2097152
    const size_t PADn = (size_t)PD * Hn;           // 2048

    // layout: [coef pad: PADn float4][coef: ETH float4][vt pad: PADn f][vt: ETH f]...
    float4* coef4 = (float4*)ws + PADn;            // pads absorb t<0 tail refills
    float*  vtbase = (float*)((float4*)ws + PADn + ETH);
    float*  vt_g  = vtbase + PADn;
    float*  rest  = vt_g + ETH;
    float* k_g    = rest;                          // BTH
    float* kk_g   = rest + BTH;
    float* vraw_g = rest + 2 * BTH;
    float* sv_g   = rest + 3 * BTH;
    float* r_g    = rest + 4 * BTH;                // EB*H
    float* g_g    = r_g + EBn * Hn;
    float* sh_g   = g_g + EBn * Hn;                // EB*NH
    float* o_raw  = sh_g + EBn * NHn;              // EB*H

    kA<<<Bqn * Tln, Hn, 0, stream>>>(keyval, x_k, x_v, Wk, Wv, v0, v1, v2, k_k,
                                     k_g, kk_g, vraw_g, sv_g);
    kB<<<EBn * Tln, Hn, 0, stream>>>(query, keyval, x_w, x_a, w0, w1, w2, a0, a1, a2,
                                     k_a, k_g, kk_g, vraw_g, sv_g, v_first,
                                     coef4, vt_g);
    kR<<<EBn, Hn, 0, stream>>>(query, keyval, x_r, x_g, Wr, g1, g2, r_k, coef4,
                               r_g, g_g, sh_g);
    kScan<<<EBn * NHn, HDn, 0, stream>>>(coef4, vt_g, r_g, o_raw);
    kD<<<EBn, Hn, 0, stream>>>(o_raw, gn_w, gn_b, sh_g, vt_g, g_g, Wo, (float*)d_out);
}